// Round 1
// baseline (525.622 us; speedup 1.0000x reference)
//
#include <hip/hip_runtime.h>

#define N_WIDTH 64
#define N_ORDER 4
#define N_ELEMENTS 250
#define N_NODES 1001                        // N_ELEMENTS*N_ORDER+1
#define N_COLL 200
#define NDIM 2
#define MM 5                                // N_ORDER+1
#define ROW (N_NODES * NDIM)                // 2002 floats per (k) row
#define SAMPLE_SLICE (N_WIDTH * ROW)        // 128128 floats per sample
#define SLICE4 (SAMPLE_SLICE / 4)           // 32032 float4 per sample slice
#define BUF_ELEMS ((long)N_COLL * SAMPLE_SLICE)  // 25,625,600 floats per buffer
#define COPY_BLOCKS 2048
#define RED_BLOCKS 64

__device__ __forceinline__ float wave_reduce(float v) {
    for (int off = 32; off > 0; off >>= 1) v += __shfl_down(v, off, 64);
    return v;
}

// ---------------------------------------------------------------------------
// Kernel 1: register-lean bulk pass-through copy (m13's measured-best config:
// 2048 blocks x 256 threads, float4). Branchless remap skips the sample slice
// (owned by reduce_kernel) with zero wasted iterations. Keeping this kernel
// free of the Lagrange-bases math keeps VGPR low -> all 2048 blocks resident
// (8 blocks/CU), uniform finish, full copy bandwidth.
// ---------------------------------------------------------------------------
__global__ __launch_bounds__(256) void copy_kernel(
        const int* __restrict__ samplep,
        const float4* __restrict__ a,
        const float4* __restrict__ b,
        const float4* __restrict__ c,
        float4* __restrict__ oa,
        float4* __restrict__ ob,
        float4* __restrict__ oc) {
    const long skip_lo = (long)(*samplep) * SLICE4;
    const long n4eff = BUF_ELEMS / 4 - SLICE4;   // slice excluded from index space
    long j = (long)blockIdx.x * 256 + threadIdx.x;
    const long stride = (long)COPY_BLOCKS * 256;
    for (; j < n4eff; j += stride) {
        const long i = (j >= skip_lo) ? j + SLICE4 : j;   // remap over the slice
        float4 va = a[i];
        float4 vb = b[i];
        float4 vc = c[i];
        oa[i] = va;
        ob[i] = vb;
        oc[i] = vc;
    }
}

// ---------------------------------------------------------------------------
// Kernel 2: sample-slice scatter + copy + reduce. Block k owns row k of the
// sample slice in all three buffers. Math is verbatim from the verified fused
// kernel (absmax 0.0625 pass). Register-heavy, but only 64 tiny blocks.
// ---------------------------------------------------------------------------
__global__ __launch_bounds__(256) void reduce_kernel(
        const float* __restrict__ x,
        const int* __restrict__ flagp,
        const int* __restrict__ samplep,
        const float* __restrict__ weight,
        const float* __restrict__ phi_in,
        const float* __restrict__ dphi_in,
        const float* __restrict__ ddphi_in,
        float* __restrict__ phi_out,
        float* __restrict__ dphi_out,
        float* __restrict__ ddphi_out,
        float* __restrict__ t_out) {
    const int sample = *samplep;
    const int tid = threadIdx.x;
    const int k = blockIdx.x;
    const int flag = *flagp;
    const long wbase = (long)k * ROW;
    const long base = (long)sample * SAMPLE_SLICE + wbase;

    // element lookup per input dimension (same for every k)
    float xs[NDIM];
    int nl[NDIM];
    for (int q = 0; q < NDIM; ++q) {
        xs[q] = (float)(N_NODES - 1) * x[q];            // X_MIN=0, X_MAX=1
        float id_el = floorf(xs[q] / (float)N_ORDER);
        id_el = fminf(fmaxf(id_el, 0.0f), (float)(N_ELEMENTS - 1));
        nl[q] = (int)(id_el * (float)N_ORDER);
    }

    // Lagrange bases on nodes {-1,-0.5,0,0.5,1} for both d channels
    const float nodes[MM] = {-1.0f, -0.5f, 0.0f, 0.5f, 1.0f};
    float L[NDIM][MM], dLv[NDIM][MM], ddLv[NDIM][MM];
    for (int d = 0; d < NDIM; ++d) {
        float xt = (xs[d] - ((float)nl[d] + 2.0f)) * 0.5f;
        float inv[MM][MM], r[MM][MM];
        for (int i = 0; i < MM; ++i)
            for (int kk = 0; kk < MM; ++kk) {
                inv[i][kk] = (i == kk) ? 0.0f : 1.0f / (nodes[i] - nodes[kk]);
                r[i][kk] = (xt - nodes[kk]) * inv[i][kk];
            }
        for (int i = 0; i < MM; ++i) {
            float prod = 1.0f;
            for (int kk = 0; kk < MM; ++kk) if (kk != i) prod *= r[i][kk];
            L[d][i] = prod;

            float s = 0.0f;
            for (int j = 0; j < MM; ++j) if (j != i) {
                float pr = 1.0f;
                for (int kk = 0; kk < MM; ++kk) if (kk != i && kk != j) pr *= r[i][kk];
                s += inv[i][j] * pr;
            }
            dLv[d][i] = (i == MM - 1) ? s : 0.0f;  // reference quirk: only i==M-1 kept

            float ss = 0.0f;
            for (int j = 0; j < MM; ++j) if (j != i) {
                float s2 = 0.0f;
                for (int kk = 0; kk < MM; ++kk) if (kk != i && kk != j) {
                    float pr = 1.0f;
                    for (int l = 0; l < MM; ++l) if (l != i && l != j && l != kk) pr *= r[i][l];
                    s2 += inv[i][kk] * pr;
                }
                ss += inv[i][j] * s2;
            }
            ddLv[d][i] = ss;
        }
    }

    const float dx = 0.5f * (float)N_ORDER / (float)(N_NODES - 1);  // 0.002
    const float inv_dx = 1.0f / dx;
    const float inv_dx2 = inv_dx * inv_dx;

    float st = 0.0f, sdt = 0.0f, sddt = 0.0f;
    for (int i = tid; i < ROW; i += 256) {
        float v   = phi_in[base + i];
        float dv  = dphi_in[base + i];
        float ddv = ddphi_in[base + i];
        if (flag == 0) {
            int q = i >> 1;
            int d = i & 1;
            // final reference write at (q,d): largest valid p over dq ranges
            int p0 = q - nl[0];
            int p1 = q - nl[1];
            int p = -1;
            if (p0 >= 0 && p0 <= N_ORDER) p = p0;
            if (p1 >= 0 && p1 <= N_ORDER && p1 > p) p = p1;
            if (p >= 0) {
                v   = L[d][p];
                dv  = dLv[d][p] * inv_dx;
                ddv = ddLv[d][p] * inv_dx2;
            }
        }
        phi_out[base + i]   = v;
        dphi_out[base + i]  = dv;
        ddphi_out[base + i] = ddv;
        float wv = weight[wbase + i];
        st   += wv * v;
        sdt  += wv * dv;
        sddt += wv * ddv;
    }

    st = wave_reduce(st);
    sdt = wave_reduce(sdt);
    sddt = wave_reduce(sddt);

    __shared__ float sh[3][4];
    int lane = tid & 63;
    int wid = tid >> 6;
    if (lane == 0) { sh[0][wid] = st; sh[1][wid] = sdt; sh[2][wid] = sddt; }
    __syncthreads();
    if (tid == 0) {
        t_out[k]       = sh[0][0] + sh[0][1] + sh[0][2] + sh[0][3];
        t_out[64 + k]  = sh[1][0] + sh[1][1] + sh[1][2] + sh[1][3];
        t_out[128 + k] = sh[2][0] + sh[2][1] + sh[2][2] + sh[2][3];
    }
}

extern "C" void kernel_launch(void* const* d_in, const int* in_sizes, int n_in,
                              void* d_out, int out_size, void* d_ws, size_t ws_size,
                              hipStream_t stream) {
    const float* x        = (const float*)d_in[0];
    const int*   flagp    = (const int*)d_in[1];
    const int*   samplep  = (const int*)d_in[2];
    const float* weight   = (const float*)d_in[3];
    const float* phi_in   = (const float*)d_in[4];
    const float* dphi_in  = (const float*)d_in[5];
    const float* ddphi_in = (const float*)d_in[6];

    float* out = (float*)d_out;
    float* t_out     = out;             // 192 floats: t(64), dt(64), ddt(64)
    float* phi_out   = out + 192;       // 768 B offset -> 16B aligned
    float* dphi_out  = phi_out + BUF_ELEMS;
    float* ddphi_out = dphi_out + BUF_ELEMS;

    // Disjoint output regions; tiny kernel first, bulk copy second.
    reduce_kernel<<<RED_BLOCKS, 256, 0, stream>>>(
        x, flagp, samplep, weight, phi_in, dphi_in, ddphi_in,
        phi_out, dphi_out, ddphi_out, t_out);

    copy_kernel<<<COPY_BLOCKS, 256, 0, stream>>>(
        samplep,
        (const float4*)phi_in, (const float4*)dphi_in, (const float4*)ddphi_in,
        (float4*)phi_out, (float4*)dphi_out, (float4*)ddphi_out);
}

// Round 2
// 503.963 us; speedup vs baseline: 1.0430x; 1.0430x over previous
//
#include <hip/hip_runtime.h>

#define N_WIDTH 64
#define N_ORDER 4
#define N_ELEMENTS 250
#define N_NODES 1001                        // N_ELEMENTS*N_ORDER+1
#define N_COLL 200
#define NDIM 2
#define MM 5                                // N_ORDER+1
#define ROW (N_NODES * NDIM)                // 2002 floats per (k) row
#define SAMPLE_SLICE (N_WIDTH * ROW)        // 128128 floats per sample
#define SLICE4 (SAMPLE_SLICE / 4)           // 32032 float4 per sample slice
#define BUF_ELEMS ((long)N_COLL * SAMPLE_SLICE)  // 25,625,600 floats per buffer
#define COPY_BLOCKS 2048
#define RED_BLOCKS 64

typedef float f32x4 __attribute__((ext_vector_type(4)));

__device__ __forceinline__ float wave_reduce(float v) {
    for (int off = 32; off > 0; off >>= 1) v += __shfl_down(v, off, 64);
    return v;
}

// ---------------------------------------------------------------------------
// Single fused kernel (round-0 structure, proven 511.5 us).
//   Blocks [0, COPY_BLOCKS): interleaved float4 pass-through of all three
//     buffers, skipping the sample slice. NEW: input loads are non-temporal
//     (nt flag, no cache allocation) so the harness's poison-dirty output
//     lines stay resident in L2/L3 until our stores overwrite them -> the
//     poison data never wastes HBM writeback bandwidth.
//   Blocks [COPY_BLOCKS, +64): block k owns row k of the sample slice —
//     scatter values applied inline + t/dt/ddt reduction. Disjoint regions,
//     no ordering hazard, full overlap in one dispatch.
// ---------------------------------------------------------------------------
__global__ void fused_kernel(const float* __restrict__ x,
                             const int* __restrict__ flagp,
                             const int* __restrict__ samplep,
                             const float* __restrict__ weight,
                             const float* __restrict__ phi_in,
                             const float* __restrict__ dphi_in,
                             const float* __restrict__ ddphi_in,
                             float* __restrict__ phi_out,
                             float* __restrict__ dphi_out,
                             float* __restrict__ ddphi_out,
                             float* __restrict__ t_out) {
    const int sample = *samplep;
    const int tid = threadIdx.x;

    if (blockIdx.x < COPY_BLOCKS) {
        // ------------------ bulk pass-through copy ------------------
        const long skip_lo = (long)sample * SLICE4;
        const long skip_hi = skip_lo + SLICE4;
        const f32x4* __restrict__ a = (const f32x4*)phi_in;
        const f32x4* __restrict__ b = (const f32x4*)dphi_in;
        const f32x4* __restrict__ c = (const f32x4*)ddphi_in;
        f32x4* __restrict__ oa = (f32x4*)phi_out;
        f32x4* __restrict__ ob = (f32x4*)dphi_out;
        f32x4* __restrict__ oc = (f32x4*)ddphi_out;
        const long n4 = BUF_ELEMS / 4;
        long i = (long)blockIdx.x * 256 + tid;
        const long stride = (long)COPY_BLOCKS * 256;
        for (; i < n4; i += stride) {
            if (i >= skip_lo && i < skip_hi) continue;   // owned by reduce blocks
            f32x4 va = __builtin_nontemporal_load(a + i);
            f32x4 vb = __builtin_nontemporal_load(b + i);
            f32x4 vc = __builtin_nontemporal_load(c + i);
            oa[i] = va;   // regular stores: hit poison-dirty lines in cache
            ob[i] = vb;
            oc[i] = vc;
        }
        return;
    }

    // ------------------ sample-slice row k: scatter + copy + reduce ---------
    const int k = blockIdx.x - COPY_BLOCKS;
    const int flag = *flagp;
    const long wbase = (long)k * ROW;
    const long base = (long)sample * SAMPLE_SLICE + wbase;

    // element lookup per input dimension (same for every k)
    float xs[NDIM];
    int nl[NDIM];
    for (int q = 0; q < NDIM; ++q) {
        xs[q] = (float)(N_NODES - 1) * x[q];            // X_MIN=0, X_MAX=1
        float id_el = floorf(xs[q] / (float)N_ORDER);
        id_el = fminf(fmaxf(id_el, 0.0f), (float)(N_ELEMENTS - 1));
        nl[q] = (int)(id_el * (float)N_ORDER);
    }

    // Lagrange bases on nodes {-1,-0.5,0,0.5,1} for both d channels
    const float nodes[MM] = {-1.0f, -0.5f, 0.0f, 0.5f, 1.0f};
    float L[NDIM][MM], dLv[NDIM][MM], ddLv[NDIM][MM];
    for (int d = 0; d < NDIM; ++d) {
        float xt = (xs[d] - ((float)nl[d] + 2.0f)) * 0.5f;
        float inv[MM][MM], r[MM][MM];
        for (int i = 0; i < MM; ++i)
            for (int kk = 0; kk < MM; ++kk) {
                inv[i][kk] = (i == kk) ? 0.0f : 1.0f / (nodes[i] - nodes[kk]);
                r[i][kk] = (xt - nodes[kk]) * inv[i][kk];
            }
        for (int i = 0; i < MM; ++i) {
            float prod = 1.0f;
            for (int kk = 0; kk < MM; ++kk) if (kk != i) prod *= r[i][kk];
            L[d][i] = prod;

            float s = 0.0f;
            for (int j = 0; j < MM; ++j) if (j != i) {
                float pr = 1.0f;
                for (int kk = 0; kk < MM; ++kk) if (kk != i && kk != j) pr *= r[i][kk];
                s += inv[i][j] * pr;
            }
            dLv[d][i] = (i == MM - 1) ? s : 0.0f;  // reference quirk: only i==M-1 kept

            float ss = 0.0f;
            for (int j = 0; j < MM; ++j) if (j != i) {
                float s2 = 0.0f;
                for (int kk = 0; kk < MM; ++kk) if (kk != i && kk != j) {
                    float pr = 1.0f;
                    for (int l = 0; l < MM; ++l) if (l != i && l != j && l != kk) pr *= r[i][l];
                    s2 += inv[i][kk] * pr;
                }
                ss += inv[i][j] * s2;
            }
            ddLv[d][i] = ss;
        }
    }

    const float dx = 0.5f * (float)N_ORDER / (float)(N_NODES - 1);  // 0.002
    const float inv_dx = 1.0f / dx;
    const float inv_dx2 = inv_dx * inv_dx;

    float st = 0.0f, sdt = 0.0f, sddt = 0.0f;
    for (int i = tid; i < ROW; i += 256) {
        float v   = phi_in[base + i];
        float dv  = dphi_in[base + i];
        float ddv = ddphi_in[base + i];
        if (flag == 0) {
            int q = i >> 1;
            int d = i & 1;
            // final reference write at (q,d): largest valid p over dq ranges
            int p0 = q - nl[0];
            int p1 = q - nl[1];
            int p = -1;
            if (p0 >= 0 && p0 <= N_ORDER) p = p0;
            if (p1 >= 0 && p1 <= N_ORDER && p1 > p) p = p1;
            if (p >= 0) {
                v   = L[d][p];
                dv  = dLv[d][p] * inv_dx;
                ddv = ddLv[d][p] * inv_dx2;
            }
        }
        phi_out[base + i]   = v;
        dphi_out[base + i]  = dv;
        ddphi_out[base + i] = ddv;
        float wv = weight[wbase + i];
        st   += wv * v;
        sdt  += wv * dv;
        sddt += wv * ddv;
    }

    st = wave_reduce(st);
    sdt = wave_reduce(sdt);
    sddt = wave_reduce(sddt);

    __shared__ float sh[3][4];
    int lane = tid & 63;
    int wid = tid >> 6;
    if (lane == 0) { sh[0][wid] = st; sh[1][wid] = sdt; sh[2][wid] = sddt; }
    __syncthreads();
    if (tid == 0) {
        t_out[k]       = sh[0][0] + sh[0][1] + sh[0][2] + sh[0][3];
        t_out[64 + k]  = sh[1][0] + sh[1][1] + sh[1][2] + sh[1][3];
        t_out[128 + k] = sh[2][0] + sh[2][1] + sh[2][2] + sh[2][3];
    }
}

extern "C" void kernel_launch(void* const* d_in, const int* in_sizes, int n_in,
                              void* d_out, int out_size, void* d_ws, size_t ws_size,
                              hipStream_t stream) {
    const float* x        = (const float*)d_in[0];
    const int*   flagp    = (const int*)d_in[1];
    const int*   samplep  = (const int*)d_in[2];
    const float* weight   = (const float*)d_in[3];
    const float* phi_in   = (const float*)d_in[4];
    const float* dphi_in  = (const float*)d_in[5];
    const float* ddphi_in = (const float*)d_in[6];

    float* out = (float*)d_out;
    float* t_out     = out;             // 192 floats: t(64), dt(64), ddt(64)
    float* phi_out   = out + 192;       // 768 B offset -> 16B aligned
    float* dphi_out  = phi_out + BUF_ELEMS;
    float* ddphi_out = dphi_out + BUF_ELEMS;

    fused_kernel<<<COPY_BLOCKS + RED_BLOCKS, 256, 0, stream>>>(
        x, flagp, samplep, weight, phi_in, dphi_in, ddphi_in,
        phi_out, dphi_out, ddphi_out, t_out);
}